// Round 1
// baseline (288.394 us; speedup 1.0000x reference)
//
#include <hip/hip_runtime.h>

#define BB   16
#define FIN  16
#define FOUT 16
#define HH   384
#define WW   384
#define LAT  512
#define NMIX 8
#define HW   (HH * WW)          // 147456
#define HW4  (HW / 4)           // 36864 float4 per channel plane

// ---------------------------------------------------------------------------
// Kernel 1: fold lat -> mix -> per-sample (kernel, bias). Tiny (1 block).
//   kbuf: [B][FOUT][FIN]   bbuf: [B][FOUT]
// ---------------------------------------------------------------------------
__global__ __launch_bounds__(256)
void mix_prep_kernel(const float* __restrict__ lat,
                     const float* __restrict__ kernel_mix,   // [NMIX][FOUT][FIN]
                     const float* __restrict__ bias_mix,     // [NMIX][FOUT]
                     const float* __restrict__ w_dyn,        // [NMIX][LAT]
                     const float* __restrict__ b_dyn,        // [NMIX]
                     float* __restrict__ kbuf,
                     float* __restrict__ bbuf) {
    __shared__ float mix_s[BB][NMIX];
    const int t = threadIdx.x;

    // threads 0..127: one (b, m) dot product of length 512 each (vectorized x4)
    if (t < BB * NMIX) {
        const int b = t / NMIX, m = t % NMIX;
        const float4* lv = (const float4*)(lat + (size_t)b * LAT);
        const float4* wv = (const float4*)(w_dyn + (size_t)m * LAT);
        float acc = 0.f;
#pragma unroll 8
        for (int j = 0; j < LAT / 4; ++j) {
            float4 a = lv[j], w = wv[j];
            acc += a.x * w.x + a.y * w.y + a.z * w.z + a.w * w.w;
        }
        mix_s[b][m] = acc + b_dyn[m];
    }
    __syncthreads();

    // all 256 threads: thread t -> (b = t/16, o = t%16); fold NMIX mixtures
    const int b = t / FOUT, o = t % FOUT;
    float kacc[FIN];
#pragma unroll
    for (int i = 0; i < FIN; ++i) kacc[i] = 0.f;
    float bacc = 0.f;
#pragma unroll
    for (int m = 0; m < NMIX; ++m) {
        const float c = mix_s[b][m];
        bacc += c * bias_mix[m * FOUT + o];
#pragma unroll
        for (int i = 0; i < FIN; ++i)
            kacc[i] += c * kernel_mix[(m * FOUT + o) * FIN + i];
    }
    bbuf[b * FOUT + o] = bacc;
#pragma unroll
    for (int i = 0; i < FIN; ++i)
        kbuf[(b * FOUT + o) * FIN + i] = kacc[i];
}

// ---------------------------------------------------------------------------
// Kernel 2: per-pixel 16x16 matvec, float4-vectorized over W.
// grid = (HW4/256, B), block = 256. Each thread: 4 pixels, all 16 channels.
// Weight reads use block-uniform indices -> scalar loads, cached.
// ---------------------------------------------------------------------------
__global__ __launch_bounds__(256)
void mixconv_main(const float* __restrict__ x,
                  const float* __restrict__ kbuf,
                  const float* __restrict__ bbuf,
                  float* __restrict__ out) {
    const int b = blockIdx.y;
    const int p = blockIdx.x * 256 + threadIdx.x;   // float4 index in [0, HW4)

    const float4* xv = (const float4*)(x + (size_t)b * FIN * HW) + p;
    float4*       ov = (float4*)(out + (size_t)b * FOUT * HW) + p;

    float4 xi[FIN];
#pragma unroll
    for (int i = 0; i < FIN; ++i) xi[i] = xv[(size_t)i * HW4];

    const float* k  = kbuf + b * FOUT * FIN;
    const float* bv = bbuf + b * FOUT;

#pragma unroll
    for (int o = 0; o < FOUT; ++o) {
        const float bo = bv[o];
        float4 acc;
        acc.x = bo; acc.y = bo; acc.z = bo; acc.w = bo;
#pragma unroll
        for (int i = 0; i < FIN; ++i) {
            const float kv = k[o * FIN + i];
            acc.x += kv * xi[i].x;
            acc.y += kv * xi[i].y;
            acc.z += kv * xi[i].z;
            acc.w += kv * xi[i].w;
        }
        ov[(size_t)o * HW4] = acc;
    }
}

// ---------------------------------------------------------------------------
extern "C" void kernel_launch(void* const* d_in, const int* in_sizes, int n_in,
                              void* d_out, int out_size, void* d_ws, size_t ws_size,
                              hipStream_t stream) {
    const float* x          = (const float*)d_in[0];
    const float* lat        = (const float*)d_in[1];
    const float* kernel_mix = (const float*)d_in[2];
    const float* bias_mix   = (const float*)d_in[3];
    const float* w_dyn      = (const float*)d_in[4];
    const float* b_dyn      = (const float*)d_in[5];
    float* out = (float*)d_out;

    float* kbuf = (float*)d_ws;                    // B*FOUT*FIN = 4096 floats
    float* bbuf = kbuf + BB * FOUT * FIN;          // B*FOUT     = 256 floats

    mix_prep_kernel<<<dim3(1), dim3(256), 0, stream>>>(
        lat, kernel_mix, bias_mix, w_dyn, b_dyn, kbuf, bbuf);

    dim3 grid(HW4 / 256, BB);                      // (144, 16) = 2304 blocks
    mixconv_main<<<grid, dim3(256), 0, stream>>>(x, kbuf, bbuf, out);
}

// Round 2
// 260.397 us; speedup vs baseline: 1.1075x; 1.1075x over previous
//
#include <hip/hip_runtime.h>

#define BB   16
#define FIN  16
#define FOUT 16
#define HH   384
#define WW   384
#define LAT  512
#define NMIX 8
#define HW   (HH * WW)          // 147456
#define HW4  (HW / 4)           // 36864 float4 per channel plane

typedef float f32x4 __attribute__((ext_vector_type(4)));

// ---------------------------------------------------------------------------
// Single fused kernel. Each block (one of 144 per sample, 16 samples):
//   phase 1: recompute mix[8] = lat[b]·w_dyn^T + b_dyn   (block-redundant, L2-hot)
//   phase 2: fold per-sample kernel[16][16] + bias[16] into LDS
//   phase 3: streaming 16x16 matvec over this block's 256 float4 pixel groups
// Weight reads in phase 3 are wave-uniform LDS b128 -> broadcast, conflict-free.
// x/out are stream-once -> nontemporal hints.
// ---------------------------------------------------------------------------
__global__ __launch_bounds__(256)
void mixconv_fused(const float* __restrict__ x,
                   const float* __restrict__ lat,
                   const float* __restrict__ kernel_mix,   // [NMIX][FOUT][FIN]
                   const float* __restrict__ bias_mix,     // [NMIX][FOUT]
                   const float* __restrict__ w_dyn,        // [NMIX][LAT]
                   const float* __restrict__ b_dyn,        // [NMIX]
                   float* __restrict__ out) {
    __shared__ float part[NMIX][32];
    __shared__ float mix_s[NMIX];
    __shared__ float ksh[FOUT][FIN];
    __shared__ float bsh[FOUT];

    const int t = threadIdx.x;
    const int b = blockIdx.y;

    // ---- phase 1: mix[m] = lat[b] . w_dyn[m] + b_dyn[m] -------------------
    {
        const int m = t & (NMIX - 1);       // 0..7
        const int c = t >> 3;               // 0..31, chunk of 16 elements
        const f32x4* lv = (const f32x4*)(lat + (size_t)b * LAT + c * 16);
        const f32x4* wv = (const f32x4*)(w_dyn + (size_t)m * LAT + c * 16);
        float acc = 0.f;
#pragma unroll
        for (int j = 0; j < 4; ++j) {
            f32x4 a = lv[j], w = wv[j];
            acc += a.x * w.x + a.y * w.y + a.z * w.z + a.w * w.w;
        }
        part[m][c] = acc;
    }
    __syncthreads();
    if (t < NMIX) {
        float s = 0.f;
#pragma unroll
        for (int c = 0; c < 32; ++c) s += part[t][c];
        mix_s[t] = s + b_dyn[t];
    }
    __syncthreads();

    // ---- phase 2: fold per-sample weights into LDS -------------------------
    {
        // thread t -> (o = t>>4, i = t&15); global reads coalesced (addr = m*256 + t)
        float kacc = 0.f;
#pragma unroll
        for (int m = 0; m < NMIX; ++m)
            kacc += mix_s[m] * kernel_mix[m * FOUT * FIN + t];
        ((float*)ksh)[t] = kacc;
        if (t < FOUT) {
            float bacc = 0.f;
#pragma unroll
            for (int m = 0; m < NMIX; ++m)
                bacc += mix_s[m] * bias_mix[m * FOUT + t];
            bsh[t] = bacc;
        }
    }
    __syncthreads();

    // ---- phase 3: streaming matvec ----------------------------------------
    const int p = blockIdx.x * 256 + t;     // float4 index in [0, HW4)
    const f32x4* xv = (const f32x4*)(x + (size_t)b * FIN * HW) + p;
    f32x4*       ov = (f32x4*)(out + (size_t)b * FOUT * HW) + p;

    f32x4 xi[FIN];
#pragma unroll
    for (int i = 0; i < FIN; ++i)
        xi[i] = __builtin_nontemporal_load(xv + (size_t)i * HW4);

#pragma unroll
    for (int o = 0; o < FOUT; ++o) {
        const f32x4 k0 = *(const f32x4*)&ksh[o][0];
        const f32x4 k1 = *(const f32x4*)&ksh[o][4];
        const f32x4 k2 = *(const f32x4*)&ksh[o][8];
        const f32x4 k3 = *(const f32x4*)&ksh[o][12];
        const float bo = bsh[o];
        f32x4 acc = {bo, bo, bo, bo};
        acc += k0.x * xi[0];  acc += k0.y * xi[1];
        acc += k0.z * xi[2];  acc += k0.w * xi[3];
        acc += k1.x * xi[4];  acc += k1.y * xi[5];
        acc += k1.z * xi[6];  acc += k1.w * xi[7];
        acc += k2.x * xi[8];  acc += k2.y * xi[9];
        acc += k2.z * xi[10]; acc += k2.w * xi[11];
        acc += k3.x * xi[12]; acc += k3.y * xi[13];
        acc += k3.z * xi[14]; acc += k3.w * xi[15];
        __builtin_nontemporal_store(acc, ov + (size_t)o * HW4);
    }
}

// ---------------------------------------------------------------------------
extern "C" void kernel_launch(void* const* d_in, const int* in_sizes, int n_in,
                              void* d_out, int out_size, void* d_ws, size_t ws_size,
                              hipStream_t stream) {
    const float* x          = (const float*)d_in[0];
    const float* lat        = (const float*)d_in[1];
    const float* kernel_mix = (const float*)d_in[2];
    const float* bias_mix   = (const float*)d_in[3];
    const float* w_dyn      = (const float*)d_in[4];
    const float* b_dyn      = (const float*)d_in[5];
    float* out = (float*)d_out;

    dim3 grid(HW4 / 256, BB);               // (144, 16) = 2304 blocks
    mixconv_fused<<<grid, dim3(256), 0, stream>>>(
        x, lat, kernel_mix, bias_mix, w_dyn, b_dyn, out);
}

// Round 3
// 255.003 us; speedup vs baseline: 1.1309x; 1.0212x over previous
//
#include <hip/hip_runtime.h>

#define BB   16
#define FIN  16
#define FOUT 16
#define HH   384
#define WW   384
#define LAT  512
#define NMIX 8
#define HW   (HH * WW)          // 147456
#define HW4  (HW / 4)           // 36864 float4 per channel plane

typedef float f32x4 __attribute__((ext_vector_type(4)));

// ---------------------------------------------------------------------------
// Single fused kernel, load-first ordering:
//   phase 0: issue all 16 nontemporal x loads (long-latency HBM) immediately
//   phase 1: mix[8] = lat[b]·w_dyn^T + b_dyn  (block-redundant, L2-hot)
//   phase 2: fold per-sample kernel[16][16] + bias[16] into LDS
//   phase 3: consume x regs: 16x16 matvec, nontemporal stores
// Weight reads in phase 3 are wave-uniform LDS b128 -> broadcast, conflict-free.
// ---------------------------------------------------------------------------
__global__ __launch_bounds__(256)
void mixconv_fused(const float* __restrict__ x,
                   const float* __restrict__ lat,
                   const float* __restrict__ kernel_mix,   // [NMIX][FOUT][FIN]
                   const float* __restrict__ bias_mix,     // [NMIX][FOUT]
                   const float* __restrict__ w_dyn,        // [NMIX][LAT]
                   const float* __restrict__ b_dyn,        // [NMIX]
                   float* __restrict__ out) {
    __shared__ float part[NMIX][32];
    __shared__ float mix_s[NMIX];
    __shared__ float ksh[FOUT][FIN];
    __shared__ float bsh[FOUT];

    const int t = threadIdx.x;
    const int b = blockIdx.y;

    // ---- phase 0: issue streaming x loads first ---------------------------
    const int p = blockIdx.x * 256 + t;     // float4 index in [0, HW4)
    const f32x4* xv = (const f32x4*)(x + (size_t)b * FIN * HW) + p;
    f32x4*       ov = (f32x4*)(out + (size_t)b * FOUT * HW) + p;

    f32x4 xi[FIN];
#pragma unroll
    for (int i = 0; i < FIN; ++i)
        xi[i] = __builtin_nontemporal_load(xv + (size_t)i * HW4);

    // ---- phase 1: mix[m] = lat[b] . w_dyn[m] + b_dyn[m] -------------------
    {
        const int m = t & (NMIX - 1);       // 0..7
        const int c = t >> 3;               // 0..31, chunk of 16 elements
        const f32x4* lv = (const f32x4*)(lat + (size_t)b * LAT + c * 16);
        const f32x4* wv = (const f32x4*)(w_dyn + (size_t)m * LAT + c * 16);
        float acc = 0.f;
#pragma unroll
        for (int j = 0; j < 4; ++j) {
            f32x4 a = lv[j], w = wv[j];
            acc += a.x * w.x + a.y * w.y + a.z * w.z + a.w * w.w;
        }
        part[m][c] = acc;
    }
    __syncthreads();
    if (t < NMIX) {
        float s = 0.f;
#pragma unroll
        for (int c = 0; c < 32; ++c) s += part[t][c];
        mix_s[t] = s + b_dyn[t];
    }
    __syncthreads();

    // ---- phase 2: fold per-sample weights into LDS -------------------------
    {
        // thread t -> (o = t>>4, i = t&15); global reads coalesced (addr = m*256 + t)
        float kacc = 0.f;
#pragma unroll
        for (int m = 0; m < NMIX; ++m)
            kacc += mix_s[m] * kernel_mix[m * FOUT * FIN + t];
        ((float*)ksh)[t] = kacc;
        if (t < FOUT) {
            float bacc = 0.f;
#pragma unroll
            for (int m = 0; m < NMIX; ++m)
                bacc += mix_s[m] * bias_mix[m * FOUT + t];
            bsh[t] = bacc;
        }
    }
    __syncthreads();

    // ---- phase 3: consume x, matvec, stream out ---------------------------
#pragma unroll
    for (int o = 0; o < FOUT; ++o) {
        const f32x4 k0 = *(const f32x4*)&ksh[o][0];
        const f32x4 k1 = *(const f32x4*)&ksh[o][4];
        const f32x4 k2 = *(const f32x4*)&ksh[o][8];
        const f32x4 k3 = *(const f32x4*)&ksh[o][12];
        const float bo = bsh[o];
        f32x4 acc = {bo, bo, bo, bo};
        acc += k0.x * xi[0];  acc += k0.y * xi[1];
        acc += k0.z * xi[2];  acc += k0.w * xi[3];
        acc += k1.x * xi[4];  acc += k1.y * xi[5];
        acc += k1.z * xi[6];  acc += k1.w * xi[7];
        acc += k2.x * xi[8];  acc += k2.y * xi[9];
        acc += k2.z * xi[10]; acc += k2.w * xi[11];
        acc += k3.x * xi[12]; acc += k3.y * xi[13];
        acc += k3.z * xi[14]; acc += k3.w * xi[15];
        __builtin_nontemporal_store(acc, ov + (size_t)o * HW4);
    }
}

// ---------------------------------------------------------------------------
extern "C" void kernel_launch(void* const* d_in, const int* in_sizes, int n_in,
                              void* d_out, int out_size, void* d_ws, size_t ws_size,
                              hipStream_t stream) {
    const float* x          = (const float*)d_in[0];
    const float* lat        = (const float*)d_in[1];
    const float* kernel_mix = (const float*)d_in[2];
    const float* bias_mix   = (const float*)d_in[3];
    const float* w_dyn      = (const float*)d_in[4];
    const float* b_dyn      = (const float*)d_in[5];
    float* out = (float*)d_out;

    dim3 grid(HW4 / 256, BB);               // (144, 16) = 2304 blocks
    mixconv_fused<<<grid, dim3(256), 0, stream>>>(
        x, lat, kernel_mix, bias_mix, w_dyn, b_dyn, out);
}